// Round 2
// baseline (520.487 us; speedup 1.0000x reference)
//
#include <hip/hip_runtime.h>
#include <hip/hip_bf16.h>
#include <stdint.h>

// MHA forward: B=2, S=2048, D=2048, H=16, DK=128. mask is all-ones (unused by reference).
#define B_  2
#define S_  2048
#define D_  2048
#define H_  16
#define DK_ 128
#define E3_ 6144   // 3*D

typedef __attribute__((ext_vector_type(8))) __bf16 bf16x8;
typedef __attribute__((ext_vector_type(4))) __bf16 bf16x4;
typedef __attribute__((ext_vector_type(4))) float f32x4;

static __device__ __forceinline__ f32x4 mfma16(bf16x8 a, bf16x8 b, f32x4 c) {
  return __builtin_amdgcn_mfma_f32_16x16x32_bf16(a, b, c, 0, 0, 0);
}

// async global->LDS, 16B per lane; lds dest must be wave-uniform base (HW adds lane*16)
static __device__ __forceinline__ void gload16(const __bf16* g, __bf16* l) {
  __builtin_amdgcn_global_load_lds(
      (const __attribute__((address_space(1))) void*)g,
      (__attribute__((address_space(3))) void*)l, 16, 0, 0);
}

// ---------------- f32 -> bf16 convert (vectorized, grid-stride) ----------------
__global__ __launch_bounds__(256) void cvt_f32_bf16(const float* __restrict__ in,
                                                    __bf16* __restrict__ out, int n) {
  int i = (blockIdx.x * 256 + threadIdx.x) * 4;
  int stride = gridDim.x * 256 * 4;
  for (; i < n; i += stride) {
    float4 v = *reinterpret_cast<const float4*>(in + i);
    bf16x4 o;
    o[0] = (__bf16)v.x; o[1] = (__bf16)v.y; o[2] = (__bf16)v.z; o[3] = (__bf16)v.w;
    *reinterpret_cast<bf16x4*>(out + i) = o;
  }
}

// ---------------- GEMM: C[M][N] = A[M][K] * Bw[N][K]^T + bias ----------------
// m97 structure: 128x128 tile, BK=64, 4 waves (2x2), global_load_lds width-16
// staging into LINEAR LDS (T2 swizzle is null at 128²+2-phase; m97 = 874-912 TF).
template <bool OUT_BF16>
__global__ __launch_bounds__(256) void gemm_bt(const __bf16* __restrict__ A,
                                               const __bf16* __restrict__ Bw,
                                               const float* __restrict__ bias,
                                               void* __restrict__ Cout,
                                               int M, int N, int K) {
  __shared__ __bf16 sA[128 * 64];
  __shared__ __bf16 sB[128 * 64];
  const int tid = threadIdx.x;
  const int lane = tid & 63;
  const int w = tid >> 6;
  const int wm = w >> 1, wn = w & 1;
  const int g = lane >> 4, l15 = lane & 15;

  // XCD-aware swizzle (nwg % 8 == 0 for both our launches -> bijective)
  int nwg = gridDim.x * gridDim.y;
  int wgid = blockIdx.y * gridDim.x + blockIdx.x;
  int cpx = nwg >> 3;
  int swz = (wgid & 7) * cpx + (wgid >> 3);
  int bx = swz % gridDim.x;
  int by = swz / gridDim.x;
  const int m0 = by * 128, n0 = bx * 128;

  // staging: 16 chunks of 8 rows; wave w issues chunks w*4..w*4+3 for A and B.
  // lane l covers row chunk*8 + (l>>3), granule (l&7)*8 elems (1KB/instr, linear).
  const int srow = lane >> 3, sgran = (lane & 7) * 8;
  const __bf16* aBase = A + (size_t)(m0 + srow) * K + sgran;
  const __bf16* bBase = Bw + (size_t)(n0 + srow) * K + sgran;

  f32x4 acc[4][4] = {};

  for (int k0 = 0; k0 < K; k0 += 64) {
#pragma unroll
    for (int i = 0; i < 4; ++i) {
      int chunk = w * 4 + i;
      gload16(aBase + (size_t)(chunk * 8) * K + k0, &sA[chunk * 8 * 64]);
      gload16(bBase + (size_t)(chunk * 8) * K + k0, &sB[chunk * 8 * 64]);
    }
    __syncthreads();  // compiler drains vmcnt here -> tile ready

#pragma unroll
    for (int kc = 0; kc < 2; ++kc) {
      bf16x8 af[4], bfr[4];
#pragma unroll
      for (int i = 0; i < 4; ++i) {
        af[i] = *reinterpret_cast<const bf16x8*>(&sA[(wm * 64 + i * 16 + l15) * 64 + kc * 32 + g * 8]);
        bfr[i] = *reinterpret_cast<const bf16x8*>(&sB[(wn * 64 + i * 16 + l15) * 64 + kc * 32 + g * 8]);
      }
#pragma unroll
      for (int i = 0; i < 4; ++i)
#pragma unroll
        for (int j = 0; j < 4; ++j)
          acc[i][j] = mfma16(af[i], bfr[j], acc[i][j]);
    }
    __syncthreads();  // all waves done reading before next overwrite
  }

  // epilogue: C/D layout row=(lane>>4)*4+r, col=lane&15
  float bv[4];
#pragma unroll
  for (int j = 0; j < 4; ++j) bv[j] = bias[n0 + wn * 64 + j * 16 + l15];
#pragma unroll
  for (int i = 0; i < 4; ++i)
#pragma unroll
    for (int j = 0; j < 4; ++j)
#pragma unroll
      for (int r = 0; r < 4; ++r) {
        int grow = m0 + wm * 64 + i * 16 + g * 4 + r;
        int gcol = n0 + wn * 64 + j * 16 + l15;
        float v = acc[i][j][r] + bv[j];
        if constexpr (OUT_BF16)
          reinterpret_cast<__bf16*>(Cout)[(size_t)grow * N + gcol] = (__bf16)v;
        else
          reinterpret_cast<float*>(Cout)[(size_t)grow * N + gcol] = v;
      }
}

// ---------------- V transpose: vt[(b*H+h)*DK + d][s] = qkv[(b*S+s)*6144 + h*384+256+d] ----
__global__ __launch_bounds__(256) void transpose_v(const __bf16* __restrict__ qkv,
                                                   __bf16* __restrict__ vt) {
  __shared__ __bf16 tile[64][72];
  int s0 = blockIdx.x * 64, d0 = blockIdx.y * 64, bh = blockIdx.z;
  int b = bh >> 4, h = bh & 15;
  int t = threadIdx.x;
  int rr = t >> 4, cc = (t & 15) * 4;
#pragma unroll
  for (int p = 0; p < 4; ++p) {
    int si = p * 16 + rr;
    bf16x4 v = *reinterpret_cast<const bf16x4*>(
        qkv + (size_t)(b * S_ + s0 + si) * E3_ + h * 384 + 256 + d0 + cc);
    *reinterpret_cast<bf16x4*>(&tile[si][cc]) = v;
  }
  __syncthreads();
#pragma unroll
  for (int p = 0; p < 4; ++p) {
    int di = p * 16 + rr;
    bf16x4 o;
#pragma unroll
    for (int j = 0; j < 4; ++j) o[j] = tile[cc + j][di];
    *reinterpret_cast<bf16x4*>(vt + ((size_t)bh * DK_ + d0 + di) * S_ + s0 + cc) = o;
  }
}

// ---------------- Flash attention ----------------
// grid (S/128, B*H), 512 threads = 8 waves; wave w owns q-rows [qt*128+w*16, +16).
// K tile 64x128 in LDS stride 272B (pad), VT tile 128x64 stride 144B (pad),
// P per-wave [16][72]. Online softmax; 16x16x32 MFMA. 8 waves share each staged
// K/V tile (2x the TLP of R1, half the per-wave staging cost).
__global__ __launch_bounds__(512) void attn_fwd(const __bf16* __restrict__ qkv,
                                                const __bf16* __restrict__ vt,
                                                __bf16* __restrict__ outp) {
  __shared__ unsigned char smem[54272];
  const int K_OFF = 0, VT_OFF = 17408, P_OFF = 35840;
  const int qt = blockIdx.x, bh = blockIdx.y;
  const int b = bh >> 4, h = bh & 15;
  const int tid = threadIdx.x, lane = tid & 63, w = tid >> 6;
  const int g = lane >> 4, l15 = lane & 15;
  const float scale = 0.088388347648318447f;  // 1/sqrt(128)

  // Q fragments (A-operand: row = lane&15, k = (lane>>4)*8+e), held in regs whole kernel
  bf16x8 qf[4];
  {
    int qrow = qt * 128 + w * 16 + l15;
    const __bf16* qb = qkv + (size_t)(b * S_ + qrow) * E3_ + h * 384;
#pragma unroll
    for (int c = 0; c < 4; ++c)
      qf[c] = *reinterpret_cast<const bf16x8*>(qb + c * 32 + g * 8);
  }

  f32x4 o[8] = {};
  float m_run[4], l_run[4];
#pragma unroll
  for (int r = 0; r < 4; ++r) { m_run[r] = -INFINITY; l_run[r] = 0.f; }
  unsigned char* P_base = &smem[P_OFF + w * 2304];

  for (int kt = 0; kt < S_ / 64; ++kt) {
    __syncthreads();
    // stage K (64x128, 16 granules/row) and VT (128x64, 8 granules/row); 2+2 per thread
    int4 kr[2], vr[2];
#pragma unroll
    for (int p = 0; p < 2; ++p) {
      int gran = p * 512 + tid;
      int krow = gran >> 4, kslot = gran & 15;
      kr[p] = *reinterpret_cast<const int4*>(
          qkv + (size_t)(b * S_ + kt * 64 + krow) * E3_ + h * 384 + 128 + kslot * 8);
      int vrow = gran >> 3, vslot = gran & 7;
      vr[p] = *reinterpret_cast<const int4*>(
          vt + ((size_t)bh * DK_ + vrow) * S_ + kt * 64 + vslot * 8);
    }
#pragma unroll
    for (int p = 0; p < 2; ++p) {
      int gran = p * 512 + tid;
      int krow = gran >> 4, kslot = gran & 15;
      *reinterpret_cast<int4*>(&smem[K_OFF + krow * 272 + kslot * 16]) = kr[p];
      int vrow = gran >> 3, vslot = gran & 7;
      *reinterpret_cast<int4*>(&smem[VT_OFF + vrow * 144 + vslot * 16]) = vr[p];
    }
    __syncthreads();

    // QK^T: S-tile 16x64 per wave
    f32x4 sacc[4] = {};
#pragma unroll
    for (int c = 0; c < 4; ++c) {
      bf16x8 kb[4];
#pragma unroll
      for (int j = 0; j < 4; ++j) {
        int row = j * 16 + l15;
        kb[j] = *reinterpret_cast<const bf16x8*>(&smem[K_OFF + row * 272 + c * 64 + g * 16]);
      }
#pragma unroll
      for (int j = 0; j < 4; ++j) sacc[j] = mfma16(qf[c], kb[j], sacc[j]);
    }
#pragma unroll
    for (int j = 0; j < 4; ++j)
#pragma unroll
      for (int r = 0; r < 4; ++r) sacc[j][r] *= scale;

    // online softmax (per lane: 4 rows = g*4+r; 16-lane butterfly covers 64 cols)
    float p_val[4][4];
#pragma unroll
    for (int r = 0; r < 4; ++r) {
      float mt = fmaxf(fmaxf(sacc[0][r], sacc[1][r]), fmaxf(sacc[2][r], sacc[3][r]));
#pragma unroll
      for (int off = 1; off < 16; off <<= 1) mt = fmaxf(mt, __shfl_xor(mt, off, 64));
      float mnew = fmaxf(m_run[r], mt);
      float corr = __expf(m_run[r] - mnew);
      float sum = 0.f;
#pragma unroll
      for (int j = 0; j < 4; ++j) {
        float pv = __expf(sacc[j][r] - mnew);
        p_val[j][r] = pv;
        sum += pv;
      }
#pragma unroll
      for (int off = 1; off < 16; off <<= 1) sum += __shfl_xor(sum, off, 64);
      l_run[r] = l_run[r] * corr + sum;
      m_run[r] = mnew;
#pragma unroll
      for (int dt = 0; dt < 8; ++dt) o[dt][r] *= corr;
    }

    // P -> LDS (bf16), per-wave buffer
#pragma unroll
    for (int j = 0; j < 4; ++j)
#pragma unroll
      for (int r = 0; r < 4; ++r) {
        int row = g * 4 + r, col = j * 16 + l15;
        *reinterpret_cast<__bf16*>(&P_base[row * 144 + col * 2]) = (__bf16)p_val[j][r];
      }

    // PV: O(16x128) += P(16x64) * V(64x128)
#pragma unroll
    for (int kc = 0; kc < 2; ++kc) {
      bf16x8 pa = *reinterpret_cast<const bf16x8*>(&P_base[l15 * 144 + kc * 64 + g * 16]);
#pragma unroll
      for (int dt = 0; dt < 8; ++dt) {
        int row = dt * 16 + l15;
        bf16x8 vb =
            *reinterpret_cast<const bf16x8*>(&smem[VT_OFF + row * 144 + kc * 64 + g * 16]);
        o[dt] = mfma16(pa, vb, o[dt]);
      }
    }
  }

  // epilogue: normalize and store bf16 to [b*S+q][h*128+d]
  float inv_l[4];
#pragma unroll
  for (int r = 0; r < 4; ++r) inv_l[r] = 1.0f / l_run[r];
  int qb = qt * 128 + w * 16 + g * 4;
#pragma unroll
  for (int dt = 0; dt < 8; ++dt)
#pragma unroll
    for (int r = 0; r < 4; ++r) {
      int q = qb + r;
      outp[(size_t)(b * S_ + q) * D_ + h * DK_ + dt * 16 + l15] =
          (__bf16)(o[dt][r] * inv_l[r]);
    }
}

// ---------------- launch ----------------
extern "C" void kernel_launch(void* const* d_in, const int* in_sizes, int n_in,
                              void* d_out, int out_size, void* d_ws, size_t ws_size,
                              hipStream_t stream) {
  const float* x     = (const float*)d_in[0];
  // d_in[1] = mask (all ones, unused by reference math)
  const float* w_qkv = (const float*)d_in[2];
  const float* b_qkv = (const float*)d_in[3];
  const float* w_o   = (const float*)d_in[4];
  const float* b_o   = (const float*)d_in[5];
  float* out = (float*)d_out;

  uint8_t* ws = (uint8_t*)d_ws;
  // layout: xbf 16MB | wqkvbf 24MB | wobf 8MB | qkvbf 48MB  (~100.7MB total)
  __bf16* xbf    = (__bf16*)(ws);
  __bf16* wqkvbf = (__bf16*)(ws + 16777216);
  __bf16* wobf   = (__bf16*)(ws + 16777216 + 25165824);
  __bf16* qkvbf  = (__bf16*)(ws + 50331648);
  __bf16* vtbf   = (__bf16*)wqkvbf;  // alias: w_qkv bf16 dead after GEMM1
  __bf16* attnbf = (__bf16*)xbf;     // alias: x bf16 dead after GEMM1

  cvt_f32_bf16<<<2048, 256, 0, stream>>>(x, xbf, B_ * S_ * D_);
  cvt_f32_bf16<<<2048, 256, 0, stream>>>(w_qkv, wqkvbf, E3_ * D_);
  cvt_f32_bf16<<<2048, 256, 0, stream>>>(w_o, wobf, D_ * D_);

  dim3 g1(E3_ / 128, (B_ * S_) / 128);  // 48 x 32
  gemm_bt<true><<<g1, 256, 0, stream>>>(xbf, wqkvbf, b_qkv, qkvbf, B_ * S_, E3_, D_);

  dim3 gt(S_ / 64, DK_ / 64, B_ * H_);  // 32 x 2 x 32
  transpose_v<<<gt, 256, 0, stream>>>(qkvbf, vtbf);

  dim3 ga(S_ / 128, B_ * H_);  // 16 x 32
  attn_fwd<<<ga, 512, 0, stream>>>(qkvbf, vtbf, attnbf);

  dim3 g2(D_ / 128, (B_ * S_) / 128);  // 16 x 32
  gemm_bt<false><<<g2, 256, 0, stream>>>(attnbf, wobf, b_o, out, B_ * S_, D_, D_);
}

// Round 3
// 501.565 us; speedup vs baseline: 1.0377x; 1.0377x over previous
//
#include <hip/hip_runtime.h>
#include <hip/hip_bf16.h>
#include <stdint.h>

// MHA forward: B=2, S=2048, D=2048, H=16, DK=128. mask is all-ones (unused by reference).
#define B_  2
#define S_  2048
#define D_  2048
#define H_  16
#define DK_ 128
#define E3_ 6144   // 3*D

typedef __attribute__((ext_vector_type(8))) __bf16 bf16x8;
typedef __attribute__((ext_vector_type(4))) __bf16 bf16x4;
typedef __attribute__((ext_vector_type(4))) float f32x4;

static __device__ __forceinline__ f32x4 mfma16(bf16x8 a, bf16x8 b, f32x4 c) {
  return __builtin_amdgcn_mfma_f32_16x16x32_bf16(a, b, c, 0, 0, 0);
}

// async global->LDS, 16B per lane; lds dest must be wave-uniform base (HW adds lane*16)
static __device__ __forceinline__ void gload16(const __bf16* g, const void* l) {
  __builtin_amdgcn_global_load_lds(
      (const __attribute__((address_space(1))) void*)g,
      (__attribute__((address_space(3))) void*)l, 16, 0, 0);
}

// ---------------- f32 -> bf16 convert (vectorized, grid-stride) ----------------
__global__ __launch_bounds__(256) void cvt_f32_bf16(const float* __restrict__ in,
                                                    __bf16* __restrict__ out, int n) {
  int i = (blockIdx.x * 256 + threadIdx.x) * 4;
  int stride = gridDim.x * 256 * 4;
  for (; i < n; i += stride) {
    float4 v = *reinterpret_cast<const float4*>(in + i);
    bf16x4 o;
    o[0] = (__bf16)v.x; o[1] = (__bf16)v.y; o[2] = (__bf16)v.z; o[3] = (__bf16)v.w;
    *reinterpret_cast<bf16x4*>(out + i) = o;
  }
}

// ---------------- GEMM: C[M][N] = A[M][K] * Bw[N][K]^T + bias ----------------
// m97 structure + rule#21: global_load_lds (linear dest) with PRE-SWIZZLED global
// source, XOR-swizzled ds_reads: phys = (row*128 + colb) ^ ((row&7)<<4).
// Fragment reads become 2-way (free) instead of 16-way.
template <bool OUT_BF16>
__global__ __launch_bounds__(256) void gemm_bt(const __bf16* __restrict__ A,
                                               const __bf16* __restrict__ Bw,
                                               const float* __restrict__ bias,
                                               void* __restrict__ Cout,
                                               int M, int N, int K) {
  __shared__ __bf16 sA[128 * 64];
  __shared__ __bf16 sB[128 * 64];
  const int tid = threadIdx.x;
  const int lane = tid & 63;
  const int w = tid >> 6;
  const int wm = w >> 1, wn = w & 1;
  const int g = lane >> 4, l15 = lane & 15;

  // XCD-aware swizzle (nwg % 8 == 0 for both our launches -> bijective)
  int nwg = gridDim.x * gridDim.y;
  int wgid = blockIdx.y * gridDim.x + blockIdx.x;
  int cpx = nwg >> 3;
  int swz = (wgid & 7) * cpx + (wgid >> 3);
  int bx = swz % gridDim.x;
  int by = swz / gridDim.x;
  const int m0 = by * 128, n0 = bx * 128;

  // staging: lane l covers row chunk*8 + (l>>3); source granule pre-swizzled so that
  // the linear LDS write lands at phys = logical ^ ((row&7)<<4).
  const int srow = lane >> 3;
  const int sgran = ((lane & 7) ^ (lane >> 3)) * 8;  // row&7 == lane>>3 (chunk*8 aligned)
  const __bf16* aBase = A + (size_t)(m0 + srow) * K + sgran;
  const __bf16* bBase = Bw + (size_t)(n0 + srow) * K + sgran;

  f32x4 acc[4][4] = {};

  for (int k0 = 0; k0 < K; k0 += 64) {
#pragma unroll
    for (int i = 0; i < 4; ++i) {
      int chunk = w * 4 + i;
      gload16(aBase + (size_t)(chunk * 8) * K + k0, &sA[chunk * 8 * 64]);
      gload16(bBase + (size_t)(chunk * 8) * K + k0, &sB[chunk * 8 * 64]);
    }
    __syncthreads();  // compiler drains vmcnt here -> tile ready

#pragma unroll
    for (int kc = 0; kc < 2; ++kc) {
      bf16x8 af[4], bfr[4];
#pragma unroll
      for (int i = 0; i < 4; ++i) {
        int rowa = wm * 64 + i * 16 + l15;
        int pa = (rowa * 128 + kc * 64 + g * 16) ^ ((rowa & 7) << 4);
        af[i] = *reinterpret_cast<const bf16x8*>(&((unsigned char*)sA)[pa]);
        int rowb = wn * 64 + i * 16 + l15;
        int pb = (rowb * 128 + kc * 64 + g * 16) ^ ((rowb & 7) << 4);
        bfr[i] = *reinterpret_cast<const bf16x8*>(&((unsigned char*)sB)[pb]);
      }
#pragma unroll
      for (int i = 0; i < 4; ++i)
#pragma unroll
        for (int j = 0; j < 4; ++j)
          acc[i][j] = mfma16(af[i], bfr[j], acc[i][j]);
    }
    __syncthreads();  // all waves done reading before next overwrite
  }

  // epilogue: C/D layout row=(lane>>4)*4+r, col=lane&15
  float bv[4];
#pragma unroll
  for (int j = 0; j < 4; ++j) bv[j] = bias[n0 + wn * 64 + j * 16 + l15];
#pragma unroll
  for (int i = 0; i < 4; ++i)
#pragma unroll
    for (int j = 0; j < 4; ++j)
#pragma unroll
      for (int r = 0; r < 4; ++r) {
        int grow = m0 + wm * 64 + i * 16 + g * 4 + r;
        int gcol = n0 + wn * 64 + j * 16 + l15;
        float v = acc[i][j][r] + bv[j];
        if constexpr (OUT_BF16)
          reinterpret_cast<__bf16*>(Cout)[(size_t)grow * N + gcol] = (__bf16)v;
        else
          reinterpret_cast<float*>(Cout)[(size_t)grow * N + gcol] = v;
      }
}

// ---------------- V transpose: vt[(b*H+h)*DK + d][s] = qkv[(b*S+s)*6144 + h*384+256+d] ----
__global__ __launch_bounds__(256) void transpose_v(const __bf16* __restrict__ qkv,
                                                   __bf16* __restrict__ vt) {
  __shared__ __bf16 tile[64][72];
  int s0 = blockIdx.x * 64, d0 = blockIdx.y * 64, bh = blockIdx.z;
  int b = bh >> 4, h = bh & 15;
  int t = threadIdx.x;
  int rr = t >> 4, cc = (t & 15) * 4;
#pragma unroll
  for (int p = 0; p < 4; ++p) {
    int si = p * 16 + rr;
    bf16x4 v = *reinterpret_cast<const bf16x4*>(
        qkv + (size_t)(b * S_ + s0 + si) * E3_ + h * 384 + 256 + d0 + cc);
    *reinterpret_cast<bf16x4*>(&tile[si][cc]) = v;
  }
  __syncthreads();
#pragma unroll
  for (int p = 0; p < 4; ++p) {
    int di = p * 16 + rr;
    bf16x4 o;
#pragma unroll
    for (int j = 0; j < 4; ++j) o[j] = tile[cc + j][di];
    *reinterpret_cast<bf16x4*>(vt + ((size_t)bh * DK_ + d0 + di) * S_ + s0 + cc) = o;
  }
}

// ---------------- Flash attention (2-phase pipelined) ----------------
// grid 512 blocks (XCD-chunked remap), 512 threads = 8 waves; wave w owns 16 q-rows.
// LDS 64KB: K dbuf 2x16KB (swizzled) | V single 16KB (swizzled) | P 8x2KB (swizzled).
// Pipeline per iter: [issue K(t+1) via gload_lds] QK^T+softmax+Pwrite | barrier
// (drains V(t) and K(t+1)) | PV | barrier | [issue V(t+1)].
__global__ __launch_bounds__(512) void attn_fwd(const __bf16* __restrict__ qkv,
                                                const __bf16* __restrict__ vt,
                                                __bf16* __restrict__ outp) {
  __shared__ unsigned char smem[65536];
  const int VT_OFF = 32768, P_OFF = 49152;
  // XCD-chunked remap: 512 blocks -> each XCD gets 64 consecutive (qt,bh) ids
  int lin = blockIdx.y * gridDim.x + blockIdx.x;
  int rl = (lin & 7) * 64 + (lin >> 3);
  const int qt = rl & 15, bh = rl >> 4;
  const int b = bh >> 4, h = bh & 15;
  const int tid = threadIdx.x, lane = tid & 63, w = tid >> 6;
  const int g = lane >> 4, l15 = lane & 15;
  const float SCL2 = 0.1275255128608411f;  // log2(e)/sqrt(128)

  // per-thread staging coords (K rows: 256B = 16 granules; V rows: 128B = 8 granules)
  int krow[2], kg[2], vrow[2], vg[2];
#pragma unroll
  for (int p = 0; p < 2; ++p) {
    int Gk = p * 512 + tid;
    krow[p] = Gk >> 4; kg[p] = ((Gk & 15) ^ (krow[p] & 7)) * 8;
    int Gv = p * 512 + tid;
    vrow[p] = Gv >> 3; vg[p] = ((Gv & 7) ^ (vrow[p] & 7)) * 8;
  }
  const __bf16* kSrc = qkv + (size_t)b * S_ * E3_ + h * 384 + 128;
  const __bf16* vSrc = vt + (size_t)bh * DK_ * S_;

  // Q fragments (A-operand: row = lane&15, k = (lane>>4)*8+e), held in regs whole kernel
  bf16x8 qf[4];
  {
    int qrow = qt * 128 + w * 16 + l15;
    const __bf16* qb = qkv + (size_t)(b * S_ + qrow) * E3_ + h * 384;
#pragma unroll
    for (int c = 0; c < 4; ++c)
      qf[c] = *reinterpret_cast<const bf16x8*>(qb + c * 32 + g * 8);
  }

  f32x4 o[8] = {};
  float m_run[4], l_run[4];
#pragma unroll
  for (int r = 0; r < 4; ++r) { m_run[r] = -INFINITY; l_run[r] = 0.f; }
  unsigned char* P_base = &smem[P_OFF + w * 2048];

  // prologue: stage K(0) -> buf0, V(0)
#pragma unroll
  for (int p = 0; p < 2; ++p) {
    gload16(kSrc + (size_t)(krow[p]) * E3_ + kg[p], &smem[(p * 512 + w * 64) * 16]);
    gload16(vSrc + (size_t)vrow[p] * S_ + vg[p], &smem[VT_OFF + (p * 512 + w * 64) * 16]);
  }
  __syncthreads();

  int db = 0;
  for (int kt = 0; kt < S_ / 64; ++kt) {
    // issue K(t+1) into other K buffer (lands under this iter's compute)
    if (kt < S_ / 64 - 1) {
      int s1 = (kt + 1) * 64;
#pragma unroll
      for (int p = 0; p < 2; ++p)
        gload16(kSrc + (size_t)(s1 + krow[p]) * E3_ + kg[p],
                &smem[(db ^ 1) * 16384 + (p * 512 + w * 64) * 16]);
    }

    // QK^T: S-tile 16x64 per wave, from swizzled K buffer
    const unsigned char* Kb = &smem[db * 16384];
    f32x4 sacc[4] = {};
#pragma unroll
    for (int c = 0; c < 4; ++c) {
      bf16x8 kb[4];
#pragma unroll
      for (int j = 0; j < 4; ++j) {
        int row = j * 16 + l15;
        int ph = (row * 256 + c * 64 + g * 16) ^ ((row & 7) << 4);
        kb[j] = *reinterpret_cast<const bf16x8*>(&Kb[ph]);
      }
#pragma unroll
      for (int j = 0; j < 4; ++j) sacc[j] = mfma16(qf[c], kb[j], sacc[j]);
    }

    // online softmax in raw-score domain, scale folded into exp2
    float p_val[4][4];
#pragma unroll
    for (int r = 0; r < 4; ++r) {
      float mt = fmaxf(fmaxf(sacc[0][r], sacc[1][r]), fmaxf(sacc[2][r], sacc[3][r]));
#pragma unroll
      for (int off = 1; off < 16; off <<= 1) mt = fmaxf(mt, __shfl_xor(mt, off, 64));
      float mnew = fmaxf(m_run[r], mt);
      float corr = exp2f((m_run[r] - mnew) * SCL2);
      float sum = 0.f;
#pragma unroll
      for (int j = 0; j < 4; ++j) {
        float pv = exp2f((sacc[j][r] - mnew) * SCL2);
        p_val[j][r] = pv;
        sum += pv;
      }
#pragma unroll
      for (int off = 1; off < 16; off <<= 1) sum += __shfl_xor(sum, off, 64);
      l_run[r] = l_run[r] * corr + sum;
      m_run[r] = mnew;
#pragma unroll
      for (int dt = 0; dt < 8; ++dt) o[dt][r] *= corr;
    }

    // P -> LDS (bf16, swizzled), per-wave buffer
#pragma unroll
    for (int j = 0; j < 4; ++j)
#pragma unroll
      for (int r = 0; r < 4; ++r) {
        int row = g * 4 + r, cb = (j * 16 + l15) * 2;
        int ph = (row * 128 + cb) ^ ((row & 7) << 4);
        *reinterpret_cast<__bf16*>(&P_base[ph]) = (__bf16)p_val[j][r];
      }

    __syncthreads();  // V(t) landed for all waves; K(t+1) drained too

    // PV: O(16x128) += P(16x64) * V(64x128), V from swizzled single buffer
#pragma unroll
    for (int kc = 0; kc < 2; ++kc) {
      int php = (l15 * 128 + kc * 64 + g * 16) ^ ((l15 & 7) << 4);
      bf16x8 pa = *reinterpret_cast<const bf16x8*>(&P_base[php]);
#pragma unroll
      for (int dt = 0; dt < 8; ++dt) {
        int row = dt * 16 + l15;
        int ph = (row * 128 + kc * 64 + g * 16) ^ ((row & 7) << 4);
        bf16x8 vb = *reinterpret_cast<const bf16x8*>(&smem[VT_OFF + ph]);
        o[dt] = mfma16(pa, vb, o[dt]);
      }
    }

    __syncthreads();  // all waves done reading V before overwrite

    // issue V(t+1) (lands under next iter's QK^T+softmax)
    if (kt < S_ / 64 - 1) {
      int s1 = (kt + 1) * 64;
#pragma unroll
      for (int p = 0; p < 2; ++p)
        gload16(vSrc + (size_t)vrow[p] * S_ + s1 + vg[p],
                &smem[VT_OFF + (p * 512 + w * 64) * 16]);
    }
    db ^= 1;
  }

  // epilogue: normalize and store bf16 to [b*S+q][h*128+d]
  float inv_l[4];
#pragma unroll
  for (int r = 0; r < 4; ++r) inv_l[r] = 1.0f / l_run[r];
  int qb = qt * 128 + w * 16 + g * 4;
#pragma unroll
  for (int dt = 0; dt < 8; ++dt)
#pragma unroll
    for (int r = 0; r < 4; ++r) {
      int q = qb + r;
      outp[(size_t)(b * S_ + q) * D_ + h * DK_ + dt * 16 + l15] =
          (__bf16)(o[dt][r] * inv_l[r]);
    }
}

// ---------------- launch ----------------
extern "C" void kernel_launch(void* const* d_in, const int* in_sizes, int n_in,
                              void* d_out, int out_size, void* d_ws, size_t ws_size,
                              hipStream_t stream) {
  const float* x     = (const float*)d_in[0];
  // d_in[1] = mask (all ones, unused by reference math)
  const float* w_qkv = (const float*)d_in[2];
  const float* b_qkv = (const float*)d_in[3];
  const float* w_o   = (const float*)d_in[4];
  const float* b_o   = (const float*)d_in[5];
  float* out = (float*)d_out;

  uint8_t* ws = (uint8_t*)d_ws;
  // layout: xbf 16MB | wqkvbf 24MB | wobf 8MB | qkvbf 48MB  (~100.7MB total)
  __bf16* xbf    = (__bf16*)(ws);
  __bf16* wqkvbf = (__bf16*)(ws + 16777216);
  __bf16* wobf   = (__bf16*)(ws + 16777216 + 25165824);
  __bf16* qkvbf  = (__bf16*)(ws + 50331648);
  __bf16* vtbf   = (__bf16*)wqkvbf;  // alias: w_qkv bf16 dead after GEMM1
  __bf16* attnbf = (__bf16*)xbf;     // alias: x bf16 dead after GEMM1

  cvt_f32_bf16<<<2048, 256, 0, stream>>>(x, xbf, B_ * S_ * D_);
  cvt_f32_bf16<<<2048, 256, 0, stream>>>(w_qkv, wqkvbf, E3_ * D_);
  cvt_f32_bf16<<<2048, 256, 0, stream>>>(w_o, wobf, D_ * D_);

  dim3 g1(E3_ / 128, (B_ * S_) / 128);  // 48 x 32
  gemm_bt<true><<<g1, 256, 0, stream>>>(xbf, wqkvbf, b_qkv, qkvbf, B_ * S_, E3_, D_);

  dim3 gt(S_ / 64, DK_ / 64, B_ * H_);  // 32 x 2 x 32
  transpose_v<<<gt, 256, 0, stream>>>(qkvbf, vtbf);

  dim3 ga(S_ / 128, B_ * H_);  // 16 x 32
  attn_fwd<<<ga, 512, 0, stream>>>(qkvbf, vtbf, attnbf);

  dim3 g2(D_ / 128, (B_ * S_) / 128);  // 16 x 32
  gemm_bt<false><<<g2, 256, 0, stream>>>(attnbf, wobf, b_o, out, B_ * S_, D_, D_);
}

// Round 5
// 468.529 us; speedup vs baseline: 1.1109x; 1.0705x over previous
//
#include <hip/hip_runtime.h>
#include <hip/hip_bf16.h>
#include <stdint.h>

// MHA forward: B=2, S=2048, D=2048, H=16, DK=128. mask is all-ones (unused by reference).
#define B_  2
#define S_  2048
#define D_  2048
#define H_  16
#define DK_ 128
#define E3_ 6144   // 3*D

typedef __attribute__((ext_vector_type(8))) __bf16 bf16x8;
typedef __attribute__((ext_vector_type(4))) __bf16 bf16x4;
typedef __attribute__((ext_vector_type(4))) float f32x4;

static __device__ __forceinline__ f32x4 mfma16(bf16x8 a, bf16x8 b, f32x4 c) {
  return __builtin_amdgcn_mfma_f32_16x16x32_bf16(a, b, c, 0, 0, 0);
}

// async global->LDS, 16B per lane; lds dest must be wave-uniform base (HW adds lane*16)
static __device__ __forceinline__ void gload16(const __bf16* g, const void* l) {
  __builtin_amdgcn_global_load_lds(
      (const __attribute__((address_space(1))) void*)g,
      (__attribute__((address_space(3))) void*)l, 16, 0, 0);
}

// ---------------- f32 -> bf16 convert (vectorized, grid-stride) ----------------
__global__ __launch_bounds__(256) void cvt_f32_bf16(const float* __restrict__ in,
                                                    __bf16* __restrict__ out, int n) {
  int i = (blockIdx.x * 256 + threadIdx.x) * 4;
  int stride = gridDim.x * 256 * 4;
  for (; i < n; i += stride) {
    float4 v = *reinterpret_cast<const float4*>(in + i);
    bf16x4 o;
    o[0] = (__bf16)v.x; o[1] = (__bf16)v.y; o[2] = (__bf16)v.z; o[3] = (__bf16)v.w;
    *reinterpret_cast<bf16x4*>(out + i) = o;
  }
}

// ---------------- GEMM: C[M][N] = A[M][K] * Bw[N][K]^T + bias ----------------
// m97 structure + rule#21: global_load_lds (linear dest) with PRE-SWIZZLED global
// source, XOR-swizzled ds_reads: phys = (row*128 + colb) ^ ((row&7)<<4).
template <bool OUT_BF16>
__global__ __launch_bounds__(256) void gemm_bt(const __bf16* __restrict__ A,
                                               const __bf16* __restrict__ Bw,
                                               const float* __restrict__ bias,
                                               void* __restrict__ Cout,
                                               int M, int N, int K) {
  __shared__ __bf16 sA[128 * 64];
  __shared__ __bf16 sB[128 * 64];
  const int tid = threadIdx.x;
  const int lane = tid & 63;
  const int w = tid >> 6;
  const int wm = w >> 1, wn = w & 1;
  const int g = lane >> 4, l15 = lane & 15;

  // XCD-aware swizzle (nwg % 8 == 0 for both our launches -> bijective)
  int nwg = gridDim.x * gridDim.y;
  int wgid = blockIdx.y * gridDim.x + blockIdx.x;
  int cpx = nwg >> 3;
  int swz = (wgid & 7) * cpx + (wgid >> 3);
  int bx = swz % gridDim.x;
  int by = swz / gridDim.x;
  const int m0 = by * 128, n0 = bx * 128;

  const int srow = lane >> 3;
  const int sgran = ((lane & 7) ^ (lane >> 3)) * 8;  // pre-swizzled source granule
  const __bf16* aBase = A + (size_t)(m0 + srow) * K + sgran;
  const __bf16* bBase = Bw + (size_t)(n0 + srow) * K + sgran;

  f32x4 acc[4][4] = {};

  for (int k0 = 0; k0 < K; k0 += 64) {
#pragma unroll
    for (int i = 0; i < 4; ++i) {
      int chunk = w * 4 + i;
      gload16(aBase + (size_t)(chunk * 8) * K + k0, &sA[chunk * 8 * 64]);
      gload16(bBase + (size_t)(chunk * 8) * K + k0, &sB[chunk * 8 * 64]);
    }
    __syncthreads();

#pragma unroll
    for (int kc = 0; kc < 2; ++kc) {
      bf16x8 af[4], bfr[4];
#pragma unroll
      for (int i = 0; i < 4; ++i) {
        int rowa = wm * 64 + i * 16 + l15;
        int pa = (rowa * 128 + kc * 64 + g * 16) ^ ((rowa & 7) << 4);
        af[i] = *reinterpret_cast<const bf16x8*>(&((unsigned char*)sA)[pa]);
        int rowb = wn * 64 + i * 16 + l15;
        int pb = (rowb * 128 + kc * 64 + g * 16) ^ ((rowb & 7) << 4);
        bfr[i] = *reinterpret_cast<const bf16x8*>(&((unsigned char*)sB)[pb]);
      }
#pragma unroll
      for (int i = 0; i < 4; ++i)
#pragma unroll
        for (int j = 0; j < 4; ++j)
          acc[i][j] = mfma16(af[i], bfr[j], acc[i][j]);
    }
    __syncthreads();
  }

  float bv[4];
#pragma unroll
  for (int j = 0; j < 4; ++j) bv[j] = bias[n0 + wn * 64 + j * 16 + l15];
#pragma unroll
  for (int i = 0; i < 4; ++i)
#pragma unroll
    for (int j = 0; j < 4; ++j)
#pragma unroll
      for (int r = 0; r < 4; ++r) {
        int grow = m0 + wm * 64 + i * 16 + g * 4 + r;
        int gcol = n0 + wn * 64 + j * 16 + l15;
        float v = acc[i][j][r] + bv[j];
        if constexpr (OUT_BF16)
          reinterpret_cast<__bf16*>(Cout)[(size_t)grow * N + gcol] = (__bf16)v;
        else
          reinterpret_cast<float*>(Cout)[(size_t)grow * N + gcol] = v;
      }
}

// ---------------- V transpose: vt[(b*H+h)*DK + d][s] = qkv[(b*S+s)*6144 + h*384+256+d] ----
__global__ __launch_bounds__(256) void transpose_v(const __bf16* __restrict__ qkv,
                                                   __bf16* __restrict__ vt) {
  __shared__ __bf16 tile[64][72];
  int s0 = blockIdx.x * 64, d0 = blockIdx.y * 64, bh = blockIdx.z;
  int b = bh >> 4, h = bh & 15;
  int t = threadIdx.x;
  int rr = t >> 4, cc = (t & 15) * 4;
#pragma unroll
  for (int p = 0; p < 4; ++p) {
    int si = p * 16 + rr;
    bf16x4 v = *reinterpret_cast<const bf16x4*>(
        qkv + (size_t)(b * S_ + s0 + si) * E3_ + h * 384 + 256 + d0 + cc);
    *reinterpret_cast<bf16x4*>(&tile[si][cc]) = v;
  }
  __syncthreads();
#pragma unroll
  for (int p = 0; p < 4; ++p) {
    int di = p * 16 + rr;
    bf16x4 o;
#pragma unroll
    for (int j = 0; j < 4; ++j) o[j] = tile[cc + j][di];
    *reinterpret_cast<bf16x4*>(vt + ((size_t)bh * DK_ + d0 + di) * S_ + s0 + cc) = o;
  }
}

// ---------------- Flash attention (2-phase pipelined, 48KB LDS) ----------------
// grid 512 blocks (XCD-chunked remap), 512 threads = 8 waves; wave w owns 16 q-rows.
// LDS 48KB: K dbuf 2x16KB (swizzled) | V single 16KB (swizzled). P (2KB/wave) is
// ALIASED into K[db] after barrier #1 (QK^T reads of K[db] complete; region dead
// until K(t+2) staging, which is issued only after barrier #2).
// Softmax: Q pre-scaled by log2(e)/sqrt(dk) -> scores in exp2 domain; T13 defer-max
// (skip O-rescale unless tile max exceeds running max by >8); lazy per-lane l
// (single butterfly in epilogue).
__global__ __launch_bounds__(512) void attn_fwd(const __bf16* __restrict__ qkv,
                                                const __bf16* __restrict__ vt,
                                                __bf16* __restrict__ outp) {
  __shared__ unsigned char smem[49152];
  const int VT_OFF = 32768;
  // XCD-chunked remap: each XCD gets 64 consecutive ids -> 4 bh values (K/V fit 4MB L2)
  int lin = blockIdx.y * gridDim.x + blockIdx.x;
  int rl = (lin & 7) * 64 + (lin >> 3);
  const int qt = rl & 15, bh = rl >> 4;
  const int b = bh >> 4, h = bh & 15;
  const int tid = threadIdx.x, lane = tid & 63, w = tid >> 6;
  const int g = lane >> 4, l15 = lane & 15;
  const float SCL2 = 0.1275255128608411f;  // log2(e)/sqrt(128)

  // per-thread staging coords (K rows: 256B = 16 granules; V rows: 128B = 8 granules)
  int krow[2], kg[2], vrow[2], vg[2];
#pragma unroll
  for (int p = 0; p < 2; ++p) {
    int Gk = p * 512 + tid;
    krow[p] = Gk >> 4; kg[p] = ((Gk & 15) ^ (krow[p] & 7)) * 8;
    int Gv = p * 512 + tid;
    vrow[p] = Gv >> 3; vg[p] = ((Gv & 7) ^ (vrow[p] & 7)) * 8;
  }
  const __bf16* kSrc = qkv + (size_t)b * S_ * E3_ + h * 384 + 128;
  const __bf16* vSrc = vt + (size_t)bh * DK_ * S_;

  // Q fragments, pre-scaled by SCL2 (scores land in exp2 domain)
  bf16x8 qf[4];
  {
    int qrow = qt * 128 + w * 16 + l15;
    const __bf16* qb = qkv + (size_t)(b * S_ + qrow) * E3_ + h * 384;
#pragma unroll
    for (int c = 0; c < 4; ++c) {
      bf16x8 t = *reinterpret_cast<const bf16x8*>(qb + c * 32 + g * 8);
#pragma unroll
      for (int e = 0; e < 8; ++e) qf[c][e] = (__bf16)((float)t[e] * SCL2);
    }
  }

  f32x4 o[8] = {};
  float m_run[4], l_part[4];
#pragma unroll
  for (int r = 0; r < 4; ++r) { m_run[r] = -INFINITY; l_part[r] = 0.f; }

  // prologue: stage K(0) -> buf0, V(0)
#pragma unroll
  for (int p = 0; p < 2; ++p) {
    gload16(kSrc + (size_t)(krow[p]) * E3_ + kg[p], &smem[(p * 512 + w * 64) * 16]);
    gload16(vSrc + (size_t)vrow[p] * S_ + vg[p], &smem[VT_OFF + (p * 512 + w * 64) * 16]);
  }
  __syncthreads();

  int db = 0;
  for (int kt = 0; kt < S_ / 64; ++kt) {
    // issue K(t+1) into other K buffer (lands under this iter's compute)
    if (kt < S_ / 64 - 1) {
      int s1 = (kt + 1) * 64;
#pragma unroll
      for (int p = 0; p < 2; ++p)
        gload16(kSrc + (size_t)(s1 + krow[p]) * E3_ + kg[p],
                &smem[(db ^ 1) * 16384 + (p * 512 + w * 64) * 16]);
    }

    // QK^T: S-tile 16x64 per wave, from swizzled K buffer
    const unsigned char* Kb = &smem[db * 16384];
    f32x4 sacc[4] = {};
#pragma unroll
    for (int c = 0; c < 4; ++c) {
      bf16x8 kb[4];
#pragma unroll
      for (int j = 0; j < 4; ++j) {
        int row = j * 16 + l15;
        int ph = (row * 256 + c * 64 + g * 16) ^ ((row & 7) << 4);
        kb[j] = *reinterpret_cast<const bf16x8*>(&Kb[ph]);
      }
#pragma unroll
      for (int j = 0; j < 4; ++j) sacc[j] = mfma16(qf[c], kb[j], sacc[j]);
    }

    // online softmax, exp2 domain; defer-max + lazy l
    float p_val[4][4], mt_arr[4];
    bool need = false;
#pragma unroll
    for (int r = 0; r < 4; ++r) {
      float mt = fmaxf(fmaxf(sacc[0][r], sacc[1][r]), fmaxf(sacc[2][r], sacc[3][r]));
#pragma unroll
      for (int off = 1; off < 16; off <<= 1) mt = fmaxf(mt, __shfl_xor(mt, off, 64));
      mt_arr[r] = mt;
      need = need || (mt > m_run[r] + 8.0f);
    }
    if (__any((int)need)) {
#pragma unroll
      for (int r = 0; r < 4; ++r) {
        float mnew = fmaxf(m_run[r], mt_arr[r]);
        float corr = exp2f(m_run[r] - mnew);
        m_run[r] = mnew;
        l_part[r] *= corr;
#pragma unroll
        for (int dt = 0; dt < 8; ++dt) o[dt][r] *= corr;
      }
    }
#pragma unroll
    for (int r = 0; r < 4; ++r) {
      float s0 = 0.f;
#pragma unroll
      for (int j = 0; j < 4; ++j) {
        float pv = exp2f(sacc[j][r] - m_run[r]);  // bounded by 2^8 when deferred
        p_val[j][r] = pv;
        s0 += pv;
      }
      l_part[r] += s0;
    }

    __syncthreads();  // #1: all QK^T reads of K[db] done; V(t), K(t+1) writes drained

    // P -> LDS (bf16, swizzled), aliased into K[db] per-wave slot (region dead now)
    unsigned char* P_base = &smem[db * 16384 + w * 2048];
#pragma unroll
    for (int j = 0; j < 4; ++j)
#pragma unroll
      for (int r = 0; r < 4; ++r) {
        int row = g * 4 + r, cb = (j * 16 + l15) * 2;
        int ph = (row * 128 + cb) ^ ((row & 7) << 4);
        *reinterpret_cast<__bf16*>(&P_base[ph]) = (__bf16)p_val[j][r];
      }

    // PV: O(16x128) += P(16x64) * V(64x128), V from swizzled single buffer
#pragma unroll
    for (int kc = 0; kc < 2; ++kc) {
      int php = (l15 * 128 + kc * 64 + g * 16) ^ ((l15 & 7) << 4);
      bf16x8 pa = *reinterpret_cast<const bf16x8*>(&P_base[php]);
#pragma unroll
      for (int dt = 0; dt < 8; ++dt) {
        int row = dt * 16 + l15;
        int ph = (row * 128 + kc * 64 + g * 16) ^ ((row & 7) << 4);
        bf16x8 vb = *reinterpret_cast<const bf16x8*>(&smem[VT_OFF + ph]);
        o[dt] = mfma16(pa, vb, o[dt]);
      }
    }

    __syncthreads();  // #2: all waves done reading V(t) and P before overwrites

    // issue V(t+1) (lands under next iter's QK^T+softmax)
    if (kt < S_ / 64 - 1) {
      int s1 = (kt + 1) * 64;
#pragma unroll
      for (int p = 0; p < 2; ++p)
        gload16(vSrc + (size_t)vrow[p] * S_ + s1 + vg[p],
                &smem[VT_OFF + (p * 512 + w * 64) * 16]);
    }
    db ^= 1;
  }

  // epilogue: single l butterfly per row, normalize, store bf16
  float inv_l[4];
#pragma unroll
  for (int r = 0; r < 4; ++r) {
    float s = l_part[r];
#pragma unroll
    for (int off = 1; off < 16; off <<= 1) s += __shfl_xor(s, off, 64);
    inv_l[r] = 1.0f / s;
  }
  int qb = qt * 128 + w * 16 + g * 4;
#pragma unroll
  for (int dt = 0; dt < 8; ++dt)
#pragma unroll
    for (int r = 0; r < 4; ++r) {
      int q = qb + r;
      outp[(size_t)(b * S_ + q) * D_ + h * DK_ + dt * 16 + l15] =
          (__bf16)(o[dt][r] * inv_l[r]);
    }
}

// ---------------- launch ----------------
extern "C" void kernel_launch(void* const* d_in, const int* in_sizes, int n_in,
                              void* d_out, int out_size, void* d_ws, size_t ws_size,
                              hipStream_t stream) {
  const float* x     = (const float*)d_in[0];
  // d_in[1] = mask (all ones, unused by reference math)
  const float* w_qkv = (const float*)d_in[2];
  const float* b_qkv = (const float*)d_in[3];
  const float* w_o   = (const float*)d_in[4];
  const float* b_o   = (const float*)d_in[5];
  float* out = (float*)d_out;

  uint8_t* ws = (uint8_t*)d_ws;
  // layout: xbf 16MB | wqkvbf 24MB | wobf 8MB | qkvbf 48MB  (~100.7MB total)
  __bf16* xbf    = (__bf16*)(ws);
  __bf16* wqkvbf = (__bf16*)(ws + 16777216);
  __bf16* wobf   = (__bf16*)(ws + 16777216 + 25165824);
  __bf16* qkvbf  = (__bf16*)(ws + 50331648);
  __bf16* vtbf   = (__bf16*)wqkvbf;  // alias: w_qkv bf16 dead after GEMM1
  __bf16* attnbf = (__bf16*)xbf;     // alias: x bf16 dead after GEMM1

  cvt_f32_bf16<<<2048, 256, 0, stream>>>(x, xbf, B_ * S_ * D_);
  cvt_f32_bf16<<<2048, 256, 0, stream>>>(w_qkv, wqkvbf, E3_ * D_);
  cvt_f32_bf16<<<2048, 256, 0, stream>>>(w_o, wobf, D_ * D_);

  dim3 g1(E3_ / 128, (B_ * S_) / 128);  // 48 x 32
  gemm_bt<true><<<g1, 256, 0, stream>>>(xbf, wqkvbf, b_qkv, qkvbf, B_ * S_, E3_, D_);

  dim3 gt(S_ / 64, DK_ / 64, B_ * H_);  // 32 x 2 x 32
  transpose_v<<<gt, 256, 0, stream>>>(qkvbf, vtbf);

  dim3 ga(S_ / 128, B_ * H_);  // 16 x 32
  attn_fwd<<<ga, 512, 0, stream>>>(qkvbf, vtbf, attnbf);

  dim3 g2(D_ / 128, (B_ * S_) / 128);  // 16 x 32
  gemm_bt<false><<<g2, 256, 0, stream>>>(attnbf, wobf, b_o, out, B_ * S_, D_, D_);
}

// Round 6
// 423.229 us; speedup vs baseline: 1.2298x; 1.1070x over previous
//
#include <hip/hip_runtime.h>
#include <hip/hip_bf16.h>
#include <stdint.h>

// MHA forward: B=2, S=2048, D=2048, H=16, DK=128. mask is all-ones (unused by reference).
#define B_  2
#define S_  2048
#define D_  2048
#define H_  16
#define DK_ 128
#define E3_ 6144   // 3*D

typedef __attribute__((ext_vector_type(8))) __bf16 bf16x8;
typedef __attribute__((ext_vector_type(4))) __bf16 bf16x4;
typedef __attribute__((ext_vector_type(4))) float f32x4;

static __device__ __forceinline__ f32x4 mfma16(bf16x8 a, bf16x8 b, f32x4 c) {
  return __builtin_amdgcn_mfma_f32_16x16x32_bf16(a, b, c, 0, 0, 0);
}

// async global->LDS, 16B per lane; lds dest must be wave-uniform base (HW adds lane*16)
static __device__ __forceinline__ void gload16(const __bf16* g, const void* l) {
  __builtin_amdgcn_global_load_lds(
      (const __attribute__((address_space(1))) void*)g,
      (__attribute__((address_space(3))) void*)l, 16, 0, 0);
}

// ---------------- f32 -> bf16 convert (vectorized, grid-stride) ----------------
__global__ __launch_bounds__(256) void cvt_f32_bf16(const float* __restrict__ in,
                                                    __bf16* __restrict__ out, int n) {
  int i = (blockIdx.x * 256 + threadIdx.x) * 4;
  int stride = gridDim.x * 256 * 4;
  for (; i < n; i += stride) {
    float4 v = *reinterpret_cast<const float4*>(in + i);
    bf16x4 o;
    o[0] = (__bf16)v.x; o[1] = (__bf16)v.y; o[2] = (__bf16)v.z; o[3] = (__bf16)v.w;
    *reinterpret_cast<bf16x4*>(out + i) = o;
  }
}

// ---------------- GEMM: C[M][N] = A[M][K] * Bw[N][K]^T + bias ----------------
// m97 structure + rule#21: global_load_lds (linear dest) with PRE-SWIZZLED global
// source, XOR-swizzled ds_reads: phys = (row*128 + colb) ^ ((row&7)<<4).
template <bool OUT_BF16>
__global__ __launch_bounds__(256) void gemm_bt(const __bf16* __restrict__ A,
                                               const __bf16* __restrict__ Bw,
                                               const float* __restrict__ bias,
                                               void* __restrict__ Cout,
                                               int M, int N, int K) {
  __shared__ __bf16 sA[128 * 64];
  __shared__ __bf16 sB[128 * 64];
  const int tid = threadIdx.x;
  const int lane = tid & 63;
  const int w = tid >> 6;
  const int wm = w >> 1, wn = w & 1;
  const int g = lane >> 4, l15 = lane & 15;

  // XCD-aware swizzle (nwg % 8 == 0 for both our launches -> bijective)
  int nwg = gridDim.x * gridDim.y;
  int wgid = blockIdx.y * gridDim.x + blockIdx.x;
  int cpx = nwg >> 3;
  int swz = (wgid & 7) * cpx + (wgid >> 3);
  int bx = swz % gridDim.x;
  int by = swz / gridDim.x;
  const int m0 = by * 128, n0 = bx * 128;

  const int srow = lane >> 3;
  const int sgran = ((lane & 7) ^ (lane >> 3)) * 8;  // pre-swizzled source granule
  const __bf16* aBase = A + (size_t)(m0 + srow) * K + sgran;
  const __bf16* bBase = Bw + (size_t)(n0 + srow) * K + sgran;

  f32x4 acc[4][4] = {};

  for (int k0 = 0; k0 < K; k0 += 64) {
#pragma unroll
    for (int i = 0; i < 4; ++i) {
      int chunk = w * 4 + i;
      gload16(aBase + (size_t)(chunk * 8) * K + k0, &sA[chunk * 8 * 64]);
      gload16(bBase + (size_t)(chunk * 8) * K + k0, &sB[chunk * 8 * 64]);
    }
    __syncthreads();

#pragma unroll
    for (int kc = 0; kc < 2; ++kc) {
      bf16x8 af[4], bfr[4];
#pragma unroll
      for (int i = 0; i < 4; ++i) {
        int rowa = wm * 64 + i * 16 + l15;
        int pa = (rowa * 128 + kc * 64 + g * 16) ^ ((rowa & 7) << 4);
        af[i] = *reinterpret_cast<const bf16x8*>(&((unsigned char*)sA)[pa]);
        int rowb = wn * 64 + i * 16 + l15;
        int pb = (rowb * 128 + kc * 64 + g * 16) ^ ((rowb & 7) << 4);
        bfr[i] = *reinterpret_cast<const bf16x8*>(&((unsigned char*)sB)[pb]);
      }
#pragma unroll
      for (int i = 0; i < 4; ++i)
#pragma unroll
        for (int j = 0; j < 4; ++j)
          acc[i][j] = mfma16(af[i], bfr[j], acc[i][j]);
    }
    __syncthreads();
  }

  float bv[4];
#pragma unroll
  for (int j = 0; j < 4; ++j) bv[j] = bias[n0 + wn * 64 + j * 16 + l15];
#pragma unroll
  for (int i = 0; i < 4; ++i)
#pragma unroll
    for (int j = 0; j < 4; ++j)
#pragma unroll
      for (int r = 0; r < 4; ++r) {
        int grow = m0 + wm * 64 + i * 16 + g * 4 + r;
        int gcol = n0 + wn * 64 + j * 16 + l15;
        float v = acc[i][j][r] + bv[j];
        if constexpr (OUT_BF16)
          reinterpret_cast<__bf16*>(Cout)[(size_t)grow * N + gcol] = (__bf16)v;
        else
          reinterpret_cast<float*>(Cout)[(size_t)grow * N + gcol] = v;
      }
}

// ---------------- V transpose: vt[(b*H+h)*DK + d][s] = qkv[(b*S+s)*6144 + h*384+256+d] ----
__global__ __launch_bounds__(256) void transpose_v(const __bf16* __restrict__ qkv,
                                                   __bf16* __restrict__ vt) {
  __shared__ __bf16 tile[64][72];
  int s0 = blockIdx.x * 64, d0 = blockIdx.y * 64, bh = blockIdx.z;
  int b = bh >> 4, h = bh & 15;
  int t = threadIdx.x;
  int rr = t >> 4, cc = (t & 15) * 4;
#pragma unroll
  for (int p = 0; p < 4; ++p) {
    int si = p * 16 + rr;
    bf16x4 v = *reinterpret_cast<const bf16x4*>(
        qkv + (size_t)(b * S_ + s0 + si) * E3_ + h * 384 + 256 + d0 + cc);
    *reinterpret_cast<bf16x4*>(&tile[si][cc]) = v;
  }
  __syncthreads();
#pragma unroll
  for (int p = 0; p < 4; ++p) {
    int di = p * 16 + rr;
    bf16x4 o;
#pragma unroll
    for (int j = 0; j < 4; ++j) o[j] = tile[cc + j][di];
    *reinterpret_cast<bf16x4*>(vt + ((size_t)bh * DK_ + d0 + di) * S_ + s0 + cc) = o;
  }
}

// ---------------- Flash attention v3: swapped QK^T, in-register P ----------------
// grid 512 blocks (XCD-chunked remap), 256 threads = 4 waves; wave w owns 32 q-rows
// (two 16-row groups qg=0,1). LDS 48KB: K dbuf 2x16KB + V 16KB (both XOR-swizzled).
// Swapped QK^T: sacc = mfma(kb, qf) -> S^T[k][q=l15]; lane holds 16 k-scores of ONE
// q-row (k = j*16+g*4+r). Softmax: in-lane 15-fmax tree + 2 shfl_xor; per-lane
// partial l (epilogue butterfly); T13 defer-max.
// PV with RELABELED k-positions (position (g,e) <-> k=(s*2+(e>>2))*16+g*4+(e&3) on
// BOTH operands; contraction is position-wise so any bijection is valid): the PV
// A-frag is the lane's own sacc -> NO P LDS round-trip. V B-frags = 2x ds_read_b64
// at the permuted k-columns.
// Barrier-aware issue: K(t+1) after bar#1 (covered by PV), V(t+1) after bar#2
// (covered by next QK+softmax) -- never issued right before a draining barrier.
__global__ __launch_bounds__(256, 2) void attn_fwd(const __bf16* __restrict__ qkv,
                                                   const __bf16* __restrict__ vt,
                                                   __bf16* __restrict__ outp) {
  __shared__ unsigned char smem[49152];
  const int VT_OFF = 32768;
  // XCD-chunked remap: each XCD gets 64 consecutive ids -> 4 bh values (K/V fit 4MB L2)
  int lin = blockIdx.y * gridDim.x + blockIdx.x;
  int rl = (lin & 7) * 64 + (lin >> 3);
  const int qt = rl & 15, bh = rl >> 4;
  const int b = bh >> 4, h = bh & 15;
  const int tid = threadIdx.x, lane = tid & 63, w = tid >> 6;
  const int g = lane >> 4, l15 = lane & 15;
  const float SCL2 = 0.1275255128608411f;  // log2(e)/sqrt(128)

  // staging coords (256 threads): K tile 64x128 (16 gran/row), V tile 128x64 (8 gran/row)
  int krow[4], kg[4], vrow[4], vg[4];
#pragma unroll
  for (int p = 0; p < 4; ++p) {
    int Gk = p * 256 + tid;
    krow[p] = Gk >> 4; kg[p] = ((Gk & 15) ^ (krow[p] & 7)) * 8;
    int Gv = p * 256 + tid;
    vrow[p] = Gv >> 3; vg[p] = ((Gv & 7) ^ (vrow[p] & 7)) * 8;
  }
  const __bf16* kSrc = qkv + (size_t)b * S_ * E3_ + h * 384 + 128;
  const __bf16* vSrc = vt + (size_t)bh * DK_ * S_;

  // Q fragments for both q-groups, pre-scaled into exp2 domain.
  // B-operand layout: row q = l15, elements d = c*32 + g*8 + e.
  bf16x8 qf[2][4];
#pragma unroll
  for (int qg = 0; qg < 2; ++qg) {
    int qrow = qt * 128 + w * 32 + qg * 16 + l15;
    const __bf16* qb = qkv + (size_t)(b * S_ + qrow) * E3_ + h * 384;
#pragma unroll
    for (int c = 0; c < 4; ++c) {
      bf16x8 t = *reinterpret_cast<const bf16x8*>(qb + c * 32 + g * 8);
#pragma unroll
      for (int e = 0; e < 8; ++e) qf[qg][c][e] = (__bf16)((float)t[e] * SCL2);
    }
  }

  f32x4 oA[8] = {}, oB[8] = {};
  float m_run[2] = {-INFINITY, -INFINITY}, l_part[2] = {0.f, 0.f};

  // prologue: stage K(0) -> buf0, V(0)
#pragma unroll
  for (int p = 0; p < 4; ++p) {
    gload16(kSrc + (size_t)krow[p] * E3_ + kg[p], &smem[(p * 256 + w * 64) * 16]);
    gload16(vSrc + (size_t)vrow[p] * S_ + vg[p], &smem[VT_OFF + (p * 256 + w * 64) * 16]);
  }
  __syncthreads();

  int db = 0;
  for (int kt = 0; kt < S_ / 64; ++kt) {
    // ---- QK^T swapped: sacc[qg][j] = S^T[k-frag j][q=l15], k = j*16+g*4+r ----
    const unsigned char* Kb = &smem[db * 16384];
    f32x4 sacc[2][4] = {};
#pragma unroll
    for (int c = 0; c < 4; ++c) {
      bf16x8 kb[4];
#pragma unroll
      for (int j = 0; j < 4; ++j) {
        int row = j * 16 + l15;
        int ph = (row * 256 + c * 64 + g * 16) ^ ((row & 7) << 4);
        kb[j] = *reinterpret_cast<const bf16x8*>(&Kb[ph]);
      }
#pragma unroll
      for (int qg = 0; qg < 2; ++qg)
#pragma unroll
        for (int j = 0; j < 4; ++j)
          sacc[qg][j] = mfma16(kb[j], qf[qg][c], sacc[qg][j]);
    }

    // ---- softmax (exp2 domain): in-lane tree + 2 shfl; defer-max; lazy l ----
    float mtq[2];
    bool need = false;
#pragma unroll
    for (int qg = 0; qg < 2; ++qg) {
      float m01 = fmaxf(fmaxf(sacc[qg][0][0], sacc[qg][0][1]),
                        fmaxf(sacc[qg][0][2], sacc[qg][0][3]));
      float m11 = fmaxf(fmaxf(sacc[qg][1][0], sacc[qg][1][1]),
                        fmaxf(sacc[qg][1][2], sacc[qg][1][3]));
      float m21 = fmaxf(fmaxf(sacc[qg][2][0], sacc[qg][2][1]),
                        fmaxf(sacc[qg][2][2], sacc[qg][2][3]));
      float m31 = fmaxf(fmaxf(sacc[qg][3][0], sacc[qg][3][1]),
                        fmaxf(sacc[qg][3][2], sacc[qg][3][3]));
      float mt = fmaxf(fmaxf(m01, m11), fmaxf(m21, m31));
      mt = fmaxf(mt, __shfl_xor(mt, 16, 64));
      mt = fmaxf(mt, __shfl_xor(mt, 32, 64));  // full row max (4 g-holders agree)
      mtq[qg] = mt;
      need = need || (mt > m_run[qg] + 8.0f);
    }
    if (__any((int)need)) {
#pragma unroll
      for (int qg = 0; qg < 2; ++qg) {
        float mnew = fmaxf(m_run[qg], mtq[qg]);
        float corr = exp2f(m_run[qg] - mnew);
        m_run[qg] = mnew;
        l_part[qg] *= corr;
        // O rows are q = g*4+r; corr lives at lane l15=q (g-holder 0)
#pragma unroll
        for (int r = 0; r < 4; ++r) {
          float cr = __shfl(corr, g * 4 + r, 64);
          if (qg == 0) {
#pragma unroll
            for (int dt = 0; dt < 8; ++dt) oA[dt][r] *= cr;
          } else {
#pragma unroll
            for (int dt = 0; dt < 8; ++dt) oB[dt][r] *= cr;
          }
        }
      }
    }
#pragma unroll
    for (int qg = 0; qg < 2; ++qg) {
      float s0 = 0.f;
#pragma unroll
      for (int j = 0; j < 4; ++j)
#pragma unroll
        for (int r = 0; r < 4; ++r) {
          float pv = exp2f(sacc[qg][j][r] - m_run[qg]);
          sacc[qg][j][r] = pv;
          s0 += pv;
        }
      l_part[qg] += s0;
    }

    __syncthreads();  // bar#1: V(t) (issued prev iter, covered by QK+softmax) drained

    // issue K(t+1) into other K buffer (latency covered by PV below)
    if (kt < S_ / 64 - 1) {
      int s1 = (kt + 1) * 64;
#pragma unroll
      for (int p = 0; p < 4; ++p)
        gload16(kSrc + (size_t)(s1 + krow[p]) * E3_ + kg[p],
                &smem[(db ^ 1) * 16384 + (p * 256 + w * 64) * 16]);
    }

    // ---- PV with relabeled k-positions: A-frag = own sacc (no LDS P) ----
    // position (g,e) <-> k = (s*2+(e>>2))*16 + g*4 + (e&3); B-frag elements are
    // VT[d = dt*16+l15][k(g,e,s)]: two 4-elem chunks at cols s*32+g*4 and +16.
#pragma unroll
    for (int s = 0; s < 2; ++s) {
      bf16x8 pa[2];
#pragma unroll
      for (int qg = 0; qg < 2; ++qg) {
        pa[qg][0] = (__bf16)sacc[qg][s * 2][0];
        pa[qg][1] = (__bf16)sacc[qg][s * 2][1];
        pa[qg][2] = (__bf16)sacc[qg][s * 2][2];
        pa[qg][3] = (__bf16)sacc[qg][s * 2][3];
        pa[qg][4] = (__bf16)sacc[qg][s * 2 + 1][0];
        pa[qg][5] = (__bf16)sacc[qg][s * 2 + 1][1];
        pa[qg][6] = (__bf16)sacc[qg][s * 2 + 1][2];
        pa[qg][7] = (__bf16)sacc[qg][s * 2 + 1][3];
      }
#pragma unroll
      for (int dt = 0; dt < 8; ++dt) {
        int row = dt * 16 + l15;
        int c0 = (row * 128 + s * 64 + g * 8) ^ ((row & 7) << 4);
        int c1 = (row * 128 + s * 64 + 32 + g * 8) ^ ((row & 7) << 4);
        bf16x4 lo = *reinterpret_cast<const bf16x4*>(&smem[VT_OFF + c0]);
        bf16x4 hi = *reinterpret_cast<const bf16x4*>(&smem[VT_OFF + c1]);
        bf16x8 vb = __builtin_shufflevector(lo, hi, 0, 1, 2, 3, 4, 5, 6, 7);
        oA[dt] = mfma16(pa[0], vb, oA[dt]);
        oB[dt] = mfma16(pa[1], vb, oB[dt]);
      }
    }

    __syncthreads();  // bar#2: K(t+1) drained (covered by PV); V reads complete

    // issue V(t+1) (latency covered by next iter's QK^T+softmax)
    if (kt < S_ / 64 - 1) {
      int s1 = (kt + 1) * 64;
#pragma unroll
      for (int p = 0; p < 4; ++p)
        gload16(vSrc + (size_t)vrow[p] * S_ + s1 + vg[p],
                &smem[VT_OFF + (p * 256 + w * 64) * 16]);
    }
    db ^= 1;
  }

  // epilogue: l butterfly (4 g-holders per q), normalize, store bf16
#pragma unroll
  for (int qg = 0; qg < 2; ++qg) {
    float sL = l_part[qg];
    sL += __shfl_xor(sL, 16, 64);
    sL += __shfl_xor(sL, 32, 64);
    float inv = 1.0f / sL;  // inverse for q = l15, valid at every lane
    int qbase = qt * 128 + w * 32 + qg * 16;
#pragma unroll
    for (int r = 0; r < 4; ++r) {
      float ir = __shfl(inv, g * 4 + r, 64);
      int q = qbase + g * 4 + r;
#pragma unroll
      for (int dt = 0; dt < 8; ++dt) {
        float val = (qg == 0 ? oA[dt][r] : oB[dt][r]) * ir;
        outp[(size_t)(b * S_ + q) * D_ + h * DK_ + dt * 16 + l15] = (__bf16)val;
      }
    }
  }
}

// ---------------- launch ----------------
extern "C" void kernel_launch(void* const* d_in, const int* in_sizes, int n_in,
                              void* d_out, int out_size, void* d_ws, size_t ws_size,
                              hipStream_t stream) {
  const float* x     = (const float*)d_in[0];
  // d_in[1] = mask (all ones, unused by reference math)
  const float* w_qkv = (const float*)d_in[2];
  const float* b_qkv = (const float*)d_in[3];
  const float* w_o   = (const float*)d_in[4];
  const float* b_o   = (const float*)d_in[5];
  float* out = (float*)d_out;

  uint8_t* ws = (uint8_t*)d_ws;
  // layout: xbf 16MB | wqkvbf 24MB | wobf 8MB | qkvbf 48MB  (~100.7MB total)
  __bf16* xbf    = (__bf16*)(ws);
  __bf16* wqkvbf = (__bf16*)(ws + 16777216);
  __bf16* wobf   = (__bf16*)(ws + 16777216 + 25165824);
  __bf16* qkvbf  = (__bf16*)(ws + 50331648);
  __bf16* vtbf   = (__bf16*)wqkvbf;  // alias: w_qkv bf16 dead after GEMM1
  __bf16* attnbf = (__bf16*)xbf;     // alias: x bf16 dead after GEMM1

  cvt_f32_bf16<<<2048, 256, 0, stream>>>(x, xbf, B_ * S_ * D_);
  cvt_f32_bf16<<<2048, 256, 0, stream>>>(w_qkv, wqkvbf, E3_ * D_);
  cvt_f32_bf16<<<2048, 256, 0, stream>>>(w_o, wobf, D_ * D_);

  dim3 g1(E3_ / 128, (B_ * S_) / 128);  // 48 x 32
  gemm_bt<true><<<g1, 256, 0, stream>>>(xbf, wqkvbf, b_qkv, qkvbf, B_ * S_, E3_, D_);

  dim3 gt(S_ / 64, DK_ / 64, B_ * H_);  // 32 x 2 x 32
  transpose_v<<<gt, 256, 0, stream>>>(qkvbf, vtbf);

  dim3 ga(S_ / 128, B_ * H_);  // 16 x 32
  attn_fwd<<<ga, 256, 0, stream>>>(qkvbf, vtbf, attnbf);

  dim3 g2(D_ / 128, (B_ * S_) / 128);  // 16 x 32
  gemm_bt<false><<<g2, 256, 0, stream>>>(attnbf, wobf, b_o, out, B_ * S_, D_, D_);
}